// Round 3
// baseline (770.876 us; speedup 1.0000x reference)
//
#include <hip/hip_runtime.h>
#include <math.h>

#define NQ 6
#define NL 3
#define DIM 64

// ---------- compile-time CNOT-ring permutation tables ----------
constexpr int cnot_map(int k, int ctrl, int tgt) {
    const int cb = 1 << (5 - ctrl), tb = 1 << (5 - tgt);
    return (k & cb) ? (k ^ tb) : k;
}
constexpr int ring_map(int k) {
    k = cnot_map(k, 5, 0);
    k = cnot_map(k, 4, 5);
    k = cnot_map(k, 3, 4);
    k = cnot_map(k, 2, 3);
    k = cnot_map(k, 1, 2);
    k = cnot_map(k, 0, 1);
    return k;
}
struct Perms { int p[NL + 1][DIM]; };
constexpr Perms make_perms() {
    Perms P{};
    for (int k = 0; k < DIM; k++) P.p[0][k] = k;
    for (int l = 0; l < NL; l++)
        for (int k = 0; k < DIM; k++)
            P.p[l + 1][k] = P.p[l][ring_map(k)];
    return P;
}
constexpr Perms PP = make_perms();

// ---- prep kernel: M = RZ(a2)@RY(a1)@RZ(a0) in SU(2) form (m00, m01) ----
// M[g] = (m00r, m00i, m01r, m01i); m10 = -conj(m01), m11 = conj(m00).
__global__ void gate_prep(const float* __restrict__ w, float4* __restrict__ M) {
    const int g = threadIdx.x;
    if (g >= NL * NQ) return;
    const float a0 = w[g * 3 + 0], a1 = w[g * 3 + 1], a2 = w[g * 3 + 2];
    const float ch = cosf(0.5f * a1), sh = sinf(0.5f * a1);
    const float cp = cosf(0.5f * (a0 + a2)), sp = sinf(0.5f * (a0 + a2));
    const float cm = cosf(0.5f * (a0 - a2)), sm = sinf(0.5f * (a0 - a2));
    // m00 = ch*e^{-i(a0+a2)/2}, m01 = -sh*e^{+i(a0-a2)/2}
    M[g] = make_float4(ch * cp, -ch * sp, -sh * cm, -sh * sm);
}

__global__ __launch_bounds__(256, 2)  // cap 256 VGPR; live set ~160 now
void qsim_kernel(const float* __restrict__ x, const float4* __restrict__ M,
                 float* __restrict__ out, int B) {
    const int b = blockIdx.x * blockDim.x + threadIdx.x;
    if (b >= B) return;

    // ---- x[b][0..5] ----
    const float2* x2 = (const float2*)x;
    const float2 v0 = x2[b * 3 + 0];
    const float2 v1 = x2[b * 3 + 1];
    const float2 v2 = x2[b * 3 + 2];
    const float xi[NQ] = {v0.x, v0.y, v1.x, v1.y, v2.x, v2.y};

    // ---- per-sample RY half-angles: phi = (pi/2)*tanh(x) ----
    float C[NQ], S[NQ];
#pragma unroll
    for (int i = 0; i < NQ; i++) {
        const float e = __expf(2.0f * xi[i]);
        const float t = 1.0f - 2.0f * __builtin_amdgcn_rcpf(e + 1.0f);
        __sincosf(1.5707963267948966f * t, &S[i], &C[i]);
    }

    float sr[DIM], si[DIM];

    // ---- layer 0: sparse (state = |0..0>, product state builds up) ----
#pragma unroll
    for (int q = 0; q < NQ; q++) {
        asm volatile("" ::: "memory");  // keep M loads just-in-time
        const float4 m = M[q];
        const float c = C[q], s = S[q];
        // G = M @ RY(c,s): g00 = m00*c + m01*s; g01 = -m00*s + m01*c
        const float g00r = m.x * c + m.z * s, g00i = m.y * c + m.w * s;
        const float g01r = m.z * c - m.x * s, g01i = m.w * c - m.y * s;
        if (q == 0) {
            sr[0] = g00r;  si[0] = g00i;      // b0' = g00 * 1
            sr[32] = -g01r; si[32] = g01i;    // b1' = -conj(g01) * 1
        } else {
#pragma unroll
            for (int mm = 0; mm < (1 << q); mm++) {
                const int i0 = mm << (6 - q);
                const int i1 = i0 | (1 << (5 - q));
                const float ar = sr[i0], ai = si[i0];     // b1 = 0
                sr[i0] = g00r * ar - g00i * ai;
                si[i0] = g00r * ai + g00i * ar;
                sr[i1] = -(g01r * ar + g01i * ai);
                si[i1] = g01i * ar - g01r * ai;
            }
        }
    }
    // layer-0 CNOT ring absorbed into PP.p[1]

    // ---- layers 1..2: dense, through the layer's permutation ----
#pragma unroll
    for (int layer = 1; layer < NL; layer++) {
#pragma unroll
        for (int q = 0; q < NQ; q++) {
            asm volatile("" ::: "memory");
            const float4 m = M[layer * NQ + q];
            const float c = C[q], s = S[q];
            const float g00r = m.x * c + m.z * s, g00i = m.y * c + m.w * s;
            const float g01r = m.z * c - m.x * s, g01i = m.w * c - m.y * s;
            const int right = 1 << (5 - q);
#pragma unroll
            for (int l = 0; l < (1 << q); l++) {
#pragma unroll
                for (int r = 0; r < right; r++) {
                    const int i0l = (l * 2) * right + r;
                    const int i1l = i0l + right;
                    const int i0 = PP.p[layer][i0l];
                    const int i1 = PP.p[layer][i1l];
                    const float ar = sr[i0], ai = si[i0];
                    const float br = sr[i1], bi = si[i1];
                    // b0' = g00 b0 + g01 b1 ; b1' = -conj(g01) b0 + conj(g00) b1
                    sr[i0] = g00r * ar - g00i * ai + g01r * br - g01i * bi;
                    si[i0] = g00r * ai + g00i * ar + g01r * bi + g01i * br;
                    sr[i1] = -g01r * ar - g01i * ai + g00r * br + g00i * bi;
                    si[i1] = -g01r * ai + g01i * ar + g00r * bi - g00i * br;
                }
            }
        }
    }

    // ---- expvals through final permutation ----
    float acc[NQ] = {0.f, 0.f, 0.f, 0.f, 0.f, 0.f};
#pragma unroll
    for (int k = 0; k < DIM; k++) {
        const int j = PP.p[NL][k];
        const float p = sr[j] * sr[j] + si[j] * si[j];
#pragma unroll
        for (int q = 0; q < NQ; q++) {
            if (k & (1 << (5 - q))) acc[q] -= p; else acc[q] += p;
        }
    }
    float2* o2 = (float2*)out;
    o2[b * 3 + 0] = make_float2(acc[0], acc[1]);
    o2[b * 3 + 1] = make_float2(acc[2], acc[3]);
    o2[b * 3 + 2] = make_float2(acc[4], acc[5]);
}

extern "C" void kernel_launch(void* const* d_in, const int* in_sizes, int n_in,
                              void* d_out, int out_size, void* d_ws, size_t ws_size,
                              hipStream_t stream) {
    const float* x = (const float*)d_in[0];
    const float* w = (const float*)d_in[1];
    float* out = (float*)d_out;
    float4* M = (float4*)d_ws;  // 18 * 16 B
    const int B = in_sizes[0] / NQ;
    gate_prep<<<1, 64, 0, stream>>>(w, M);
    const int block = 256;
    const int grid = (B + block - 1) / block;
    qsim_kernel<<<grid, block, 0, stream>>>(x, M, out, B);
}

// Round 4
// 142.771 us; speedup vs baseline: 5.3994x; 5.3994x over previous
//
#include <hip/hip_runtime.h>
#include <math.h>

#define NQ 6
#define NL 3

// ---------- compile-time CNOT-ring permutation ----------
constexpr int cnot_map(int k, int ctrl, int tgt) {
    const int cb = 1 << (5 - ctrl), tb = 1 << (5 - tgt);
    return (k & cb) ? (k ^ tb) : k;
}
// gather map: s'[k] = s[ring_map(k)]  (validated in rounds 2/3)
constexpr int ring_map(int k) {
    k = cnot_map(k, 5, 0);
    k = cnot_map(k, 4, 5);
    k = cnot_map(k, 3, 4);
    k = cnot_map(k, 2, 3);
    k = cnot_map(k, 1, 2);
    k = cnot_map(k, 0, 1);
    return k;
}

// Lane-split layout: lane parity h holds logical indices k = (h<<5)|s, s in [0,32).
// Ring restoration tables: where each destination slot's value comes from.
struct RingTab {
    int srcslot[2][32];   // local source slot (if local)
    int recvidx[2][32];   // exchange index if cross-lane, else -1
    int stage_src[2][32]; // slot THIS lane presents at exchange i (what partner wants)
    int m;                // number of cross-lane exchanges per lane
};
constexpr RingTab make_ring() {
    RingTab T{};
    int cnt[2] = {0, 0};
    int crossdst[2][32] = {};
    int crosssrc[2][32] = {};
    for (int h = 0; h < 2; h++)
        for (int s = 0; s < 32; s++) {
            const int k = (h << 5) | s;
            const int j = ring_map(k);
            T.srcslot[h][s] = j & 31;
            T.recvidx[h][s] = -1;
            if ((j >> 5) != h) {
                crossdst[h][cnt[h]] = s;
                crosssrc[h][cnt[h]] = j & 31;
                cnt[h]++;
            }
        }
    T.m = cnt[0];  // == cnt[1] (permutation bijectivity)
    for (int i = 0; i < T.m; i++) {
        T.recvidx[0][crossdst[0][i]] = i;
        T.recvidx[1][crossdst[1][i]] = i;
        T.stage_src[0][i] = crosssrc[1][i];  // lane0 presents what lane1 wants
        T.stage_src[1][i] = crosssrc[0][i];
    }
    return T;
}
constexpr RingTab RT = make_ring();

// ---- prep kernel: M = RZ(a2)@RY(a1)@RZ(a0), SU(2) form (m00, m01) ----
__global__ void gate_prep(const float* __restrict__ w, float4* __restrict__ M) {
    const int g = threadIdx.x;
    if (g >= NL * NQ) return;
    const float a0 = w[g * 3 + 0], a1 = w[g * 3 + 1], a2 = w[g * 3 + 2];
    const float ch = cosf(0.5f * a1), sh = sinf(0.5f * a1);
    const float cp = cosf(0.5f * (a0 + a2)), sp = sinf(0.5f * (a0 + a2));
    const float cm = cosf(0.5f * (a0 - a2)), sm = sinf(0.5f * (a0 - a2));
    M[g] = make_float4(ch * cp, -ch * sp, -sh * cm, -sh * sm);
}

__global__ __launch_bounds__(256)
void qsim_kernel(const float* __restrict__ x, const float4* __restrict__ M,
                 float* __restrict__ out, int B) {
    const int tid = blockIdx.x * blockDim.x + threadIdx.x;
    const int b = tid >> 1;
    if (b >= B) return;
    const bool h0 = (tid & 1) == 0;

    // ---- x[b][0..5] (both lanes of a pair load the same row; same cacheline) ----
    const float2* x2 = (const float2*)x;
    const float2 v0 = x2[b * 3 + 0];
    const float2 v1 = x2[b * 3 + 1];
    const float2 v2 = x2[b * 3 + 2];
    const float xi[NQ] = {v0.x, v0.y, v1.x, v1.y, v2.x, v2.y};

    float C[NQ], S[NQ];
#pragma unroll
    for (int i = 0; i < NQ; i++) {
        const float e = __expf(2.0f * xi[i]);
        const float t = 1.0f - 2.0f * __builtin_amdgcn_rcpf(e + 1.0f);
        __sincosf(1.5707963267948966f * t, &S[i], &C[i]);
    }

    float ar[32], ai[32];  // amplitudes for logical k = (h<<5)|s

    // ---- layer 0 acting on |0>: product state via cascade ----
    {
        const float4 m0 = M[0];
        const float c = C[0], s = S[0];
        const float g00r = m0.x * c + m0.z * s, g00i = m0.y * c + m0.w * s;
        const float g01r = m0.z * c - m0.x * s, g01i = m0.w * c - m0.y * s;
        // col0 of G0: lane0 gets g00, lane1 gets -conj(g01)
        ar[0] = h0 ? g00r : -g01r;
        ai[0] = h0 ? g00i : g01i;
    }
#pragma unroll
    for (int q = 1; q < NQ; q++) {
        const float4 mq = M[q];
        const float c = C[q], s = S[q];
        const float g00r = mq.x * c + mq.z * s, g00i = mq.y * c + mq.w * s;
        const float g01r = mq.z * c - mq.x * s, g01i = mq.w * c - mq.y * s;
        const float Ar = g00r, Ai = g00i;          // amp factor for bit=0
        const float Br = -g01r, Bi = g01i;         // amp factor for bit=1 (-conj(g01))
        const int bbit = 1 << (5 - q);
        const int prevmask = (0x1F << (6 - q)) & 0x1F;  // bits of qubits 1..q-1
#pragma unroll
        for (int s2 = 0; s2 < 32; s2++) {
            if ((s2 & (~prevmask & 31)) == 0) {   // s2 in filled set
                const float pr = ar[s2], pi = ai[s2];
                ar[s2 | bbit] = pr * Br - pi * Bi;
                ai[s2 | bbit] = pr * Bi + pi * Br;
                ar[s2] = pr * Ar - pi * Ai;
                ai[s2] = pr * Ai + pi * Ar;
            }
        }
    }

    // ---- ring restoration: physically re-canonicalize after CNOT ring ----
    auto do_ring = [&]() {
        float rr[32], ri[32];
#pragma unroll
        for (int i = 0; i < RT.m; i++) {
            const float str = h0 ? ar[RT.stage_src[0][i]] : ar[RT.stage_src[1][i]];
            const float sti = h0 ? ai[RT.stage_src[0][i]] : ai[RT.stage_src[1][i]];
            rr[i] = __shfl_xor(str, 1, 64);
            ri[i] = __shfl_xor(sti, 1, 64);
        }
        float nr[32], ni[32];
#pragma unroll
        for (int s2 = 0; s2 < 32; s2++) {
            const int i0 = RT.recvidx[0][s2], i1 = RT.recvidx[1][s2];
            const float v0r = (i0 >= 0) ? rr[i0] : ar[RT.srcslot[0][s2]];
            const float v0i = (i0 >= 0) ? ri[i0] : ai[RT.srcslot[0][s2]];
            const float v1r = (i1 >= 0) ? rr[i1] : ar[RT.srcslot[1][s2]];
            const float v1i = (i1 >= 0) ? ri[i1] : ai[RT.srcslot[1][s2]];
            nr[s2] = h0 ? v0r : v1r;
            ni[s2] = h0 ? v0i : v1i;
        }
#pragma unroll
        for (int s2 = 0; s2 < 32; s2++) { ar[s2] = nr[s2]; ai[s2] = ni[s2]; }
    };

    auto dense_layer = [&](int layer) {
        // ---- q = 0: split gate (partner via shfl_xor) ----
        {
            const float4 mq = M[layer * NQ + 0];
            const float c = C[0], s = S[0];
            const float g00r = mq.x * c + mq.z * s, g00i = mq.y * c + mq.w * s;
            const float g01r = mq.z * c - mq.x * s, g01i = mq.w * c - mq.y * s;
            // lane0: new = g00*own + g01*partner ; lane1: new = conj(g00)*own - conj(g01)*partner
            const float alr = g00r;
            const float ali = h0 ? g00i : -g00i;
            const float gmr = h0 ? g01r : -g01r;
            const float gmi = g01i;
#pragma unroll
            for (int s2 = 0; s2 < 32; s2++) {
                const float orr = ar[s2], oii = ai[s2];
                const float prr = __shfl_xor(orr, 1, 64);
                const float pii = __shfl_xor(oii, 1, 64);
                ar[s2] = alr * orr - ali * oii + gmr * prr - gmi * pii;
                ai[s2] = alr * oii + ali * orr + gmr * pii + gmi * prr;
            }
        }
        // ---- q = 1..5: lane-local gates ----
#pragma unroll
        for (int q = 1; q < NQ; q++) {
            const float4 mq = M[layer * NQ + q];
            const float c = C[q], s = S[q];
            const float g00r = mq.x * c + mq.z * s, g00i = mq.y * c + mq.w * s;
            const float g01r = mq.z * c - mq.x * s, g01i = mq.w * c - mq.y * s;
            const int bbit = 1 << (5 - q);
#pragma unroll
            for (int s2 = 0; s2 < 32; s2++) {
                if (!(s2 & bbit)) {
                    const int t2 = s2 | bbit;
                    const float b0r = ar[s2], b0i = ai[s2];
                    const float b1r = ar[t2], b1i = ai[t2];
                    ar[s2] = g00r * b0r - g00i * b0i + g01r * b1r - g01i * b1i;
                    ai[s2] = g00r * b0i + g00i * b0r + g01r * b1i + g01i * b1r;
                    ar[t2] = -g01r * b0r - g01i * b0i + g00r * b1r + g00i * b1i;
                    ai[t2] = -g01r * b0i + g01i * b0r + g00r * b1i - g00i * b1r;
                }
            }
        }
    };

    do_ring();
    dense_layer(1);
    do_ring();
    dense_layer(2);
    do_ring();

    // ---- expvals: per-lane partials + butterfly reduce ----
    float P = 0.0f, T[5] = {0.f, 0.f, 0.f, 0.f, 0.f};
#pragma unroll
    for (int s2 = 0; s2 < 32; s2++) {
        const float p = ar[s2] * ar[s2] + ai[s2] * ai[s2];
        P += p;
#pragma unroll
        for (int q = 1; q < NQ; q++)
            if (s2 & (1 << (5 - q))) T[q - 1] += p;
    }
    float acc[NQ];
    {
        const float d = h0 ? P : -P;                  // qubit0 sign = lane parity
        acc[0] = d + __shfl_xor(d, 1, 64);
    }
    const float Ptot = P + __shfl_xor(P, 1, 64);
#pragma unroll
    for (int q = 1; q < NQ; q++) {
        const float Tt = T[q - 1] + __shfl_xor(T[q - 1], 1, 64);
        acc[q] = Ptot - 2.0f * Tt;
    }
    const int off = b * 6 + (h0 ? 0 : 3);
    out[off + 0] = acc[h0 ? 0 : 3];
    out[off + 1] = acc[h0 ? 1 : 4];
    out[off + 2] = acc[h0 ? 2 : 5];
}

extern "C" void kernel_launch(void* const* d_in, const int* in_sizes, int n_in,
                              void* d_out, int out_size, void* d_ws, size_t ws_size,
                              hipStream_t stream) {
    const float* x = (const float*)d_in[0];
    const float* w = (const float*)d_in[1];
    float* out = (float*)d_out;
    float4* M = (float4*)d_ws;  // 18 * 16 B
    const int B = in_sizes[0] / NQ;
    gate_prep<<<1, 64, 0, stream>>>(w, M);
    const int threads = 2 * B;
    const int block = 256;
    const int grid = (threads + block - 1) / block;
    qsim_kernel<<<grid, block, 0, stream>>>(x, M, out, B);
}